// Round 9
// baseline (301.266 us; speedup 1.0000x reference)
//
#include <hip/hip_runtime.h>
#include <math.h>

typedef unsigned int u32;
typedef unsigned long long u64;

#define NBKT 65536   // 16-bit prefix buckets
#define RANK_CAP 32768

// ===== Bit-exact replica of XLA's f32 tanh (ElementalIrEmitter::EmitTanh) =====
// clamp x to [-9,9]; rational poly P(x)/Q(x) in strict f32 (no FMA); |x|<0.0004 -> x
__device__ __forceinline__ float xla_tanhf(float x) {
    float xc = fminf(fmaxf(x, -9.0f), 9.0f);
    float x2 = __fmul_rn(xc, xc);
    float p = -2.76076847742355e-16f;
    p = __fadd_rn(__fmul_rn(p, x2),  2.00018790482477e-13f);
    p = __fadd_rn(__fmul_rn(p, x2), -8.60467152213735e-11f);
    p = __fadd_rn(__fmul_rn(p, x2),  5.12229709037114e-08f);
    p = __fadd_rn(__fmul_rn(p, x2),  1.48572235717979e-05f);
    p = __fadd_rn(__fmul_rn(p, x2),  6.37261928875436e-04f);
    p = __fadd_rn(__fmul_rn(p, x2),  4.89352455891786e-03f);
    p = __fmul_rn(xc, p);
    float q = 1.19825839466702e-06f;
    q = __fadd_rn(__fmul_rn(q, x2),  1.18534705686654e-04f);
    q = __fadd_rn(__fmul_rn(q, x2),  2.26843463243900e-03f);
    q = __fadd_rn(__fmul_rn(q, x2),  4.89352518554385e-03f);
    float r = p / q;                     // IEEE f32 divide
    return (fabsf(x) < 0.0004f) ? x : r;
}

// ascending u32 order of key_desc(f) == DESCENDING float order of f
__device__ __forceinline__ u32 key_desc(float f) {
    u32 u = __float_as_uint(f);
    u = (u & 0x80000000u) ? ~u : (u | 0x80000000u);
    return ~u;
}

__global__ void k_zero(u32* __restrict__ p, int n) {
    int i = blockIdx.x * blockDim.x + threadIdx.x;
    if (i < n) p[i] = 0;
}

// blocks 0-7 probe ei, blocks 8-15 probe ntype (int64 LE => odd words zero)
__global__ void k_detect2(const int* __restrict__ ei, const int* __restrict__ nt,
                          u32* __restrict__ flags) {
    int b = blockIdx.x, t = threadIdx.x;
    if (b < 8) {
        int i = b * 256 + t;
        if (ei[2 * i + 1] != 0) atomicOr(&flags[0], 1u);
    } else {
        int i = (b - 8) * 256 + t;
        if (nt[2 * i + 1] != 0) atomicOr(&flags[1], 1u);
    }
}

// XLA-exact tanh table, cluster init, bucket histogram
__global__ void k_prep(const float* __restrict__ score, float* __restrict__ s,
                       int* __restrict__ cluster, u32* __restrict__ hist, int N) {
    int i = blockIdx.x * blockDim.x + threadIdx.x;
    if (i < N) {
        float t = xla_tanhf(score[i]);
        s[i] = t;
        cluster[i] = -1;
        atomicAdd(&hist[key_desc(t) >> 16], 1u);
    }
}

// 256 blocks: block b reduces hist[b*256 .. b*256+255] -> part[b]
__global__ void k_scan1(const u32* __restrict__ hist, u32* __restrict__ part) {
    __shared__ u32 sh[256];
    int b = blockIdx.x, t = threadIdx.x;
    sh[t] = hist[b * 256 + t];
    __syncthreads();
    for (int off = 128; off > 0; off >>= 1) {
        if (t < off) sh[t] += sh[t + off];
        __syncthreads();
    }
    if (t == 0) part[b] = sh[0];
}

// 1 block: exclusive scan of part[256] -> partScan[256]; also scan[NBKT] = total
__global__ void k_scan2(const u32* __restrict__ part, u32* __restrict__ partScan,
                        u32* __restrict__ scan) {
    __shared__ u32 sh[256];
    int t = threadIdx.x;
    u32 v = part[t];
    sh[t] = v;
    __syncthreads();
    for (int off = 1; off < 256; off <<= 1) {
        u32 x = sh[t];
        u32 y = (t >= off) ? sh[t - off] : 0u;
        __syncthreads();
        sh[t] = x + y;
        __syncthreads();
    }
    partScan[t] = sh[t] - v;            // exclusive
    if (t == 255) scan[NBKT] = sh[255]; // total = N
}

// 256 blocks: block b scans its hist chunk exclusively + base -> scan
__global__ void k_scan3(const u32* __restrict__ hist, const u32* __restrict__ partScan,
                        u32* __restrict__ scan) {
    __shared__ u32 sh[256];
    int b = blockIdx.x, t = threadIdx.x;
    u32 v = hist[b * 256 + t];
    sh[t] = v;
    __syncthreads();
    for (int off = 1; off < 256; off <<= 1) {
        u32 x = sh[t];
        u32 y = (t >= off) ? sh[t - off] : 0u;
        __syncthreads();
        sh[t] = x + y;
        __syncthreads();
    }
    scan[b * 256 + t] = partScan[b] + sh[t] - v;   // exclusive + base
}

// scatter packed (key<<32 | idx) into bucket range (intra-bucket order arbitrary)
__global__ void k_scat(const float* __restrict__ s, const u32* __restrict__ scan,
                       u32* __restrict__ cursor, u64* __restrict__ pack, int N) {
    int i = blockIdx.x * blockDim.x + threadIdx.x;
    if (i < N) {
        u32 kk = key_desc(s[i]);
        u32 b = kk >> 16;
        u32 pos = scan[b] + atomicAdd(&cursor[b], 1u);
        if (pos < (u32)N) pack[pos] = ((u64)kk << 32) | (u32)i;
    }
}

// exact rank within bucket via single u64 compare (key asc, idx asc);
// fused perm-outputs for ranks < k
__global__ void k_rankperm(const u32* __restrict__ scan, const u64* __restrict__ pack,
                           u32* __restrict__ pay, const float* __restrict__ s,
                           const int* __restrict__ ntype, const u32* __restrict__ ntFlag,
                           int* __restrict__ cluster,
                           float* __restrict__ o_nt, float* __restrict__ o_perm,
                           float* __restrict__ o_vals, int k, int N) {
    int i = blockIdx.x * blockDim.x + threadIdx.x;
    if (i < N) {
        u64 pk = pack[i];
        u32 b = (u32)(pk >> 48);
        u32 lo = scan[b], hi = scan[b + 1];
        if (hi > (u32)N) hi = (u32)N;
        if (hi > lo + RANK_CAP) hi = lo + RANK_CAP;
        u32 r = lo;
        for (u32 q = lo; q < hi; ++q) r += (pack[q] < pk);
        if (r < (u32)k) {
            u32 ip = (u32)pk;
            if (ip >= (u32)N) ip = 0;      // defensive
            pay[r] = ip;
            cluster[ip] = (int)r;
            o_perm[r] = (float)ip;
            o_vals[r] = s[ip];
            int nt = (*ntFlag == 0u) ? ntype[2 * (size_t)ip] : ntype[ip];
            o_nt[r] = (float)nt;
        }
    }
}

__global__ void k_gx(const u32* __restrict__ pay, const float* __restrict__ s,
                     const float4* __restrict__ x4, float4* __restrict__ out4,
                     int k, int Dv, int N) {
    int idx = blockIdx.x * blockDim.x + threadIdx.x;
    if (idx < k * Dv) {
        int r = idx / Dv;
        int c = idx - r * Dv;
        u32 p = pay[r];
        if (p >= (u32)N) p = 0;            // defensive
        float v = s[p];
        float4 a = x4[(size_t)p * Dv + c];
        a.x *= v; a.y *= v; a.z *= v; a.w *= v;
        out4[idx] = a;
    }
}

// fused: relabel + lengths + mask + attr copy (attr read SKIPPED for masked edges)
__global__ void k_edges_attr(const int* __restrict__ ei, const u32* __restrict__ eiFlag,
                             const float* __restrict__ elen,
                             const int* __restrict__ cluster,
                             const float4* __restrict__ attr4,
                             float* __restrict__ o_ei, float* __restrict__ o_len,
                             float* __restrict__ o_mask, float4* __restrict__ o_attr4,
                             int E, int N) {
    int e = blockIdx.x * blockDim.x + threadIdx.x;
    if (e < E) {
        bool w64 = (*eiFlag == 0u);
        int a, b;
        if (w64) {
            int2 ra = ((const int2*)ei)[e];
            int2 rb = ((const int2*)ei)[(size_t)E + e];
            a = ra.x; b = rb.x;
        } else {
            a = ei[e]; b = ei[E + e];
        }
        bool ok = ((u32)a < (u32)N) && ((u32)b < (u32)N);
        int r = ok ? cluster[a] : -1;
        int c = ok ? cluster[b] : -1;
        bool m = (r >= 0) && (c >= 0);
        o_ei[e]     = m ? (float)r : 0.0f;
        o_ei[E + e] = m ? (float)c : 0.0f;
        o_len[e]    = m ? elen[e] : 0.0f;
        o_mask[e]   = m ? 1.0f : 0.0f;
        float4* dst = o_attr4 + (size_t)e * 4;
        if (m) {
            const float4* src = attr4 + (size_t)e * 4;
            dst[0] = src[0]; dst[1] = src[1]; dst[2] = src[2]; dst[3] = src[3];
        } else {
            float4 z = {0.f, 0.f, 0.f, 0.f};
            dst[0] = z; dst[1] = z; dst[2] = z; dst[3] = z;
        }
    }
}

extern "C" void kernel_launch(void* const* d_in, const int* in_sizes, int n_in,
                              void* d_out, int out_size, void* d_ws, size_t ws_size,
                              hipStream_t stream) {
    const float* x     = (const float*)d_in[0];
    const float* score = (const float*)d_in[1];
    const int*   ei    = (const int*)d_in[2];
    const float* eattr = (const float*)d_in[3];
    const int*   ntype = (const int*)d_in[4];
    const float* elen  = (const float*)d_in[5];

    const int N  = in_sizes[1];
    const int D  = in_sizes[0] / N;
    const int E  = in_sizes[5];
    const int DE = in_sizes[3] / E;
    const int k  = (N + 1) / 2;     // ceil(0.5 * N)

    // d_out is FLOAT32. RETURN-ORDER layout:
    // x_p | edge_index | edge_attr_p | node_type | perm | vals | edge_lengths | edge_mask
    float* out = (float*)d_out;
    const size_t o_xp    = 0;
    const size_t o_ei    = o_xp    + (size_t)k * D;
    const size_t o_eattr = o_ei    + 2 * (size_t)E;
    const size_t o_nt    = o_eattr + (size_t)E * DE;
    const size_t o_perm  = o_nt    + (size_t)k;
    const size_t o_vals  = o_perm  + (size_t)k;
    const size_t o_elen  = o_vals  + (size_t)k;
    const size_t o_emask = o_elen  + (size_t)E;

    char* ws = (char*)d_ws;
    u64* pack    = (u64*)ws;     ws += 8 * (size_t)N;       // 8B-aligned first
    float* s     = (float*)ws;   ws += 4 * (size_t)N;
    u32* hist    = (u32*)ws;     ws += 4 * (size_t)NBKT;
    u32* cursor  = (u32*)ws;     ws += 4 * (size_t)NBKT;    // contiguous with hist
    u32* flags   = (u32*)ws;     ws += 4 * 2;               // contiguous: zeroed together
    u32* scan    = (u32*)ws;     ws += 4 * ((size_t)NBKT + 2);
    u32* part    = (u32*)ws;     ws += 4 * 256;
    u32* partScan= (u32*)ws;     ws += 4 * 256;
    u32* pay     = (u32*)ws;     ws += 4 * (size_t)N;
    int* cluster = (int*)ws;     ws += 4 * (size_t)N;

    const int nbN = (N + 255) / 256;
    k_zero<<<(2 * NBKT + 2 + 255) / 256, 256, 0, stream>>>(hist, 2 * NBKT + 2);
    k_detect2<<<16, 256, 0, stream>>>(ei, ntype, flags);
    k_prep<<<nbN, 256, 0, stream>>>(score, s, cluster, hist, N);
    k_scan1<<<256, 256, 0, stream>>>(hist, part);
    k_scan2<<<1, 256, 0, stream>>>(part, partScan, scan);
    k_scan3<<<256, 256, 0, stream>>>(hist, partScan, scan);
    k_scat<<<nbN, 256, 0, stream>>>(s, scan, cursor, pack, N);
    k_rankperm<<<nbN, 256, 0, stream>>>(scan, pack, pay, s, ntype, &flags[1], cluster,
                                        out + o_nt, out + o_perm, out + o_vals, k, N);
    const int Dv = D / 4;
    const int gx = k * Dv;
    k_gx<<<(gx + 255) / 256, 256, 0, stream>>>(pay, s, (const float4*)x,
                                               (float4*)(out + o_xp), k, Dv, N);
    k_edges_attr<<<(E + 255) / 256, 256, 0, stream>>>(ei, &flags[0], elen, cluster,
                                                      (const float4*)eattr,
                                                      out + o_ei, out + o_elen,
                                                      out + o_emask,
                                                      (float4*)(out + o_eattr), E, N);
}

// Round 10
// 203.899 us; speedup vs baseline: 1.4775x; 1.4775x over previous
//
#include <hip/hip_runtime.h>
#include <math.h>

typedef unsigned int u32;
typedef unsigned long long u64;
typedef float f32x4 __attribute__((ext_vector_type(4)));

#define NBKT 65536   // 16-bit prefix buckets
#define RANK_CAP 32768

// ===== Bit-exact replica of XLA's f32 tanh (ElementalIrEmitter::EmitTanh) =====
__device__ __forceinline__ float xla_tanhf(float x) {
    float xc = fminf(fmaxf(x, -9.0f), 9.0f);
    float x2 = __fmul_rn(xc, xc);
    float p = -2.76076847742355e-16f;
    p = __fadd_rn(__fmul_rn(p, x2),  2.00018790482477e-13f);
    p = __fadd_rn(__fmul_rn(p, x2), -8.60467152213735e-11f);
    p = __fadd_rn(__fmul_rn(p, x2),  5.12229709037114e-08f);
    p = __fadd_rn(__fmul_rn(p, x2),  1.48572235717979e-05f);
    p = __fadd_rn(__fmul_rn(p, x2),  6.37261928875436e-04f);
    p = __fadd_rn(__fmul_rn(p, x2),  4.89352455891786e-03f);
    p = __fmul_rn(xc, p);
    float q = 1.19825839466702e-06f;
    q = __fadd_rn(__fmul_rn(q, x2),  1.18534705686654e-04f);
    q = __fadd_rn(__fmul_rn(q, x2),  2.26843463243900e-03f);
    q = __fadd_rn(__fmul_rn(q, x2),  4.89352518554385e-03f);
    float r = p / q;                     // IEEE f32 divide
    return (fabsf(x) < 0.0004f) ? x : r;
}

// ascending u32 order of key_desc(f) == DESCENDING float order of f
__device__ __forceinline__ u32 key_desc(float f) {
    u32 u = __float_as_uint(f);
    u = (u & 0x80000000u) ? ~u : (u | 0x80000000u);
    return ~u;
}

__global__ void k_zero(u32* __restrict__ p, int n) {
    int i = blockIdx.x * blockDim.x + threadIdx.x;
    if (i < n) p[i] = 0;
}

// blocks 0-7 probe ei, blocks 8-15 probe ntype (int64 LE => odd words zero)
__global__ void k_detect2(const int* __restrict__ ei, const int* __restrict__ nt,
                          u32* __restrict__ flags) {
    int b = blockIdx.x, t = threadIdx.x;
    if (b < 8) {
        int i = b * 256 + t;
        if (ei[2 * i + 1] != 0) atomicOr(&flags[0], 1u);
    } else {
        int i = (b - 8) * 256 + t;
        if (nt[2 * i + 1] != 0) atomicOr(&flags[1], 1u);
    }
}

// XLA-exact tanh table, cluster init, bucket histogram
__global__ void k_prep(const float* __restrict__ score, float* __restrict__ s,
                       int* __restrict__ cluster, u32* __restrict__ hist, int N) {
    int i = blockIdx.x * blockDim.x + threadIdx.x;
    if (i < N) {
        float t = xla_tanhf(score[i]);
        s[i] = t;
        cluster[i] = -1;
        atomicAdd(&hist[key_desc(t) >> 16], 1u);
    }
}

// 256 blocks: block b reduces hist[b*256 .. +255] -> part[b]
__global__ void k_scan1(const u32* __restrict__ hist, u32* __restrict__ part) {
    __shared__ u32 sh[256];
    int b = blockIdx.x, t = threadIdx.x;
    sh[t] = hist[b * 256 + t];
    __syncthreads();
    for (int off = 128; off > 0; off >>= 1) {
        if (t < off) sh[t] += sh[t + off];
        __syncthreads();
    }
    if (t == 0) part[b] = sh[0];
}

// 1 block: exclusive scan of part[256]; scan[NBKT] = total
__global__ void k_scan2(const u32* __restrict__ part, u32* __restrict__ partScan,
                        u32* __restrict__ scan) {
    __shared__ u32 sh[256];
    int t = threadIdx.x;
    u32 v = part[t];
    sh[t] = v;
    __syncthreads();
    for (int off = 1; off < 256; off <<= 1) {
        u32 x = sh[t];
        u32 y = (t >= off) ? sh[t - off] : 0u;
        __syncthreads();
        sh[t] = x + y;
        __syncthreads();
    }
    partScan[t] = sh[t] - v;
    if (t == 255) scan[NBKT] = sh[255];
}

// 256 blocks: chunk-local exclusive scan + base
__global__ void k_scan3(const u32* __restrict__ hist, const u32* __restrict__ partScan,
                        u32* __restrict__ scan) {
    __shared__ u32 sh[256];
    int b = blockIdx.x, t = threadIdx.x;
    u32 v = hist[b * 256 + t];
    sh[t] = v;
    __syncthreads();
    for (int off = 1; off < 256; off <<= 1) {
        u32 x = sh[t];
        u32 y = (t >= off) ? sh[t - off] : 0u;
        __syncthreads();
        sh[t] = x + y;
        __syncthreads();
    }
    scan[b * 256 + t] = partScan[b] + sh[t] - v;
}

// scatter packed (key<<32 | idx) into bucket range
__global__ void k_scat(const float* __restrict__ s, const u32* __restrict__ scan,
                       u32* __restrict__ cursor, u64* __restrict__ pack, int N) {
    int i = blockIdx.x * blockDim.x + threadIdx.x;
    if (i < N) {
        u32 kk = key_desc(s[i]);
        u32 b = kk >> 16;
        u32 pos = scan[b] + atomicAdd(&cursor[b], 1u);
        if (pos < (u32)N) pack[pos] = ((u64)kk << 32) | (u32)i;
    }
}

// exact rank within bucket (single u64 compare) + fused perm outputs
__global__ void k_rankperm(const u32* __restrict__ scan, const u64* __restrict__ pack,
                           u32* __restrict__ pay, const float* __restrict__ s,
                           const int* __restrict__ ntype, const u32* __restrict__ ntFlag,
                           int* __restrict__ cluster,
                           float* __restrict__ o_nt, float* __restrict__ o_perm,
                           float* __restrict__ o_vals, int k, int N) {
    int i = blockIdx.x * blockDim.x + threadIdx.x;
    if (i < N) {
        u64 pk = pack[i];
        u32 b = (u32)(pk >> 48);
        u32 lo = scan[b], hi = scan[b + 1];
        if (hi > (u32)N) hi = (u32)N;
        if (hi > lo + RANK_CAP) hi = lo + RANK_CAP;
        u32 r = lo;
        for (u32 q = lo; q < hi; ++q) r += (pack[q] < pk);
        if (r < (u32)k) {
            u32 ip = (u32)pk;
            if (ip >= (u32)N) ip = 0;      // defensive
            pay[r] = ip;
            cluster[ip] = (int)r;
            o_perm[r] = (float)ip;
            o_vals[r] = s[ip];
            int nt = (*ntFlag == 0u) ? ntype[2 * (size_t)ip] : ntype[ip];
            o_nt[r] = (float)nt;
        }
    }
}

__global__ void k_gx(const u32* __restrict__ pay, const float* __restrict__ s,
                     const f32x4* __restrict__ x4, f32x4* __restrict__ out4,
                     int k, int Dv, int N) {
    int idx = blockIdx.x * blockDim.x + threadIdx.x;
    if (idx < k * Dv) {
        int r = idx / Dv;
        int c = idx - r * Dv;
        u32 p = pay[r];
        if (p >= (u32)N) p = 0;            // defensive
        float v = s[p];
        f32x4 a = x4[(size_t)p * Dv + c];
        a = a * v;
        __builtin_nontemporal_store(a, out4 + idx);
    }
}

// QUAD-fused edges+attr: 4 threads per edge; every big stream lane-consecutive.
// Lane c==0 relabels + writes ei/len/mask (consecutive-float full lines);
// mask broadcast to quad via shfl; all 4 lanes conditionally copy one float4.
__global__ void k_ea(const int* __restrict__ ei, const u32* __restrict__ eiFlag,
                     const float* __restrict__ elen, const int* __restrict__ cluster,
                     const f32x4* __restrict__ attr4,
                     float* __restrict__ o_ei, float* __restrict__ o_len,
                     float* __restrict__ o_mask, f32x4* __restrict__ o_attr4,
                     int E, int N) {
    const int total = E * 4;
    const int stride = gridDim.x * blockDim.x;
    const bool w64 = (*eiFlag == 0u);
    for (int idx = blockIdx.x * blockDim.x + threadIdx.x; idx < total; idx += stride) {
        int e = idx >> 2;
        int c = idx & 3;
        int mfl = 0;
        if (c == 0) {
            int a, b;
            if (w64) {
                a = ((const int2*)ei)[e].x;
                b = ((const int2*)ei)[(size_t)E + e].x;
            } else {
                a = ei[e]; b = ei[E + e];
            }
            bool ok = ((u32)a < (u32)N) && ((u32)b < (u32)N);
            int r  = ok ? cluster[a] : -1;
            int cc = ok ? cluster[b] : -1;
            bool m = (r >= 0) && (cc >= 0);
            mfl = m ? 1 : 0;
            __builtin_nontemporal_store(m ? (float)r  : 0.0f, o_ei + e);
            __builtin_nontemporal_store(m ? (float)cc : 0.0f, o_ei + (size_t)E + e);
            __builtin_nontemporal_store(m ? elen[e] : 0.0f, o_len + e);
            __builtin_nontemporal_store(m ? 1.0f : 0.0f, o_mask + e);
        }
        int lane = threadIdx.x & 63;
        mfl = __shfl(mfl, lane & ~3);
        f32x4 v = {0.f, 0.f, 0.f, 0.f};
        if (mfl) v = attr4[idx];
        __builtin_nontemporal_store(v, o_attr4 + idx);
    }
}

extern "C" void kernel_launch(void* const* d_in, const int* in_sizes, int n_in,
                              void* d_out, int out_size, void* d_ws, size_t ws_size,
                              hipStream_t stream) {
    const float* x     = (const float*)d_in[0];
    const float* score = (const float*)d_in[1];
    const int*   ei    = (const int*)d_in[2];
    const float* eattr = (const float*)d_in[3];
    const int*   ntype = (const int*)d_in[4];
    const float* elen  = (const float*)d_in[5];

    const int N  = in_sizes[1];
    const int D  = in_sizes[0] / N;
    const int E  = in_sizes[5];
    const int DE = in_sizes[3] / E;
    const int k  = (N + 1) / 2;     // ceil(0.5 * N)

    // d_out is FLOAT32. RETURN-ORDER layout:
    // x_p | edge_index | edge_attr_p | node_type | perm | vals | edge_lengths | edge_mask
    float* out = (float*)d_out;
    const size_t o_xp    = 0;
    const size_t o_ei    = o_xp    + (size_t)k * D;
    const size_t o_eattr = o_ei    + 2 * (size_t)E;
    const size_t o_nt    = o_eattr + (size_t)E * DE;
    const size_t o_perm  = o_nt    + (size_t)k;
    const size_t o_vals  = o_perm  + (size_t)k;
    const size_t o_elen  = o_vals  + (size_t)k;
    const size_t o_emask = o_elen  + (size_t)E;

    char* ws = (char*)d_ws;
    u64* pack    = (u64*)ws;     ws += 8 * (size_t)N;       // 8B-aligned first
    float* s     = (float*)ws;   ws += 4 * (size_t)N;
    u32* hist    = (u32*)ws;     ws += 4 * (size_t)NBKT;
    u32* cursor  = (u32*)ws;     ws += 4 * (size_t)NBKT;    // contiguous with hist
    u32* flags   = (u32*)ws;     ws += 4 * 2;               // contiguous: zeroed together
    u32* scan    = (u32*)ws;     ws += 4 * ((size_t)NBKT + 2);
    u32* part    = (u32*)ws;     ws += 4 * 256;
    u32* partScan= (u32*)ws;     ws += 4 * 256;
    u32* pay     = (u32*)ws;     ws += 4 * (size_t)N;
    int* cluster = (int*)ws;     ws += 4 * (size_t)N;

    const int nbN = (N + 255) / 256;
    k_zero<<<(2 * NBKT + 2 + 255) / 256, 256, 0, stream>>>(hist, 2 * NBKT + 2);
    k_detect2<<<16, 256, 0, stream>>>(ei, ntype, flags);
    k_prep<<<nbN, 256, 0, stream>>>(score, s, cluster, hist, N);
    k_scan1<<<256, 256, 0, stream>>>(hist, part);
    k_scan2<<<1, 256, 0, stream>>>(part, partScan, scan);
    k_scan3<<<256, 256, 0, stream>>>(hist, partScan, scan);
    k_scat<<<nbN, 256, 0, stream>>>(s, scan, cursor, pack, N);
    k_rankperm<<<nbN, 256, 0, stream>>>(scan, pack, pay, s, ntype, &flags[1], cluster,
                                        out + o_nt, out + o_perm, out + o_vals, k, N);
    const int Dv = D / 4;
    const int gx = k * Dv;
    k_gx<<<(gx + 255) / 256, 256, 0, stream>>>(pay, s, (const f32x4*)x,
                                               (f32x4*)(out + o_xp), k, Dv, N);
    k_ea<<<2048, 256, 0, stream>>>(ei, &flags[0], elen, cluster,
                                   (const f32x4*)eattr,
                                   out + o_ei, out + o_elen, out + o_emask,
                                   (f32x4*)(out + o_eattr), E, N);
}